// Round 5
// baseline (144.789 us; speedup 1.0000x reference)
//
#include <hip/hip_runtime.h>

#define DEG 10
#define KK  11      // DEG+1 coefficients
#define DV  12      // number of variables
#define NP  66      // D*(D-1)/2 pairs
#define BLK 256
#define SPT 2       // samples per thread (block-strided)

// d_ws layout (floats): W[66][12] — per-pair MONOMIAL-IN-X coeffs (Horner), 12th = pad
// lambda_p(x) = sum_r W[p][r] * x^r   (range scaling + binomials folded in, fp64 prep)

__device__ __constant__ double dC[11][11] = {
 {1},
 {1,1},
 {1,2,1},
 {1,3,3,1},
 {1,4,6,4,1},
 {1,5,10,10,5,1},
 {1,6,15,20,15,6,1},
 {1,7,21,35,35,21,7,1},
 {1,8,28,56,70,56,28,8,1},
 {1,9,36,84,126,126,84,36,9,1},
 {1,10,45,120,210,252,210,120,45,10,1}};

__global__ __launch_bounds__(128)
void prep_kernel(const float* __restrict__ params,
                 const float* __restrict__ pr,
                 float* __restrict__ ws)
{
    const int p = threadIdx.x;
    if (p >= NP) return;

    // decode pair index -> (v, c), ordering: v outer (1..11), c inner ascending
    int v = 1;
    while ((v * (v + 1)) / 2 <= p) ++v;
    const int c = p - (v * (v - 1)) / 2;

    // column-c affine map t = a*x + b (span-inflated range)
    const double low  = (double)pr[c];
    const double high = (double)pr[DV + c];
    const double w    = high - low;
    const double lo   = low - 0.1 * w;
    const double hi   = high + 0.1 * w;
    const double a    = 1.0 / (hi - lo);
    const double b    = -lo / (hi - lo);

    // Bernstein -> monomial in t:  m_j = sum_{k<=j} p_k C(10,k) C(10-k, j-k) (-1)^{j-k}
    double m[KK];
    for (int j = 0; j < KK; ++j) {
        double s = 0.0;
        for (int k = 0; k <= j; ++k) {
            double term = (double)params[k * NP + p] * dC[10][k] * dC[10 - k][j - k];
            s += ((j - k) & 1) ? -term : term;
        }
        m[j] = s;
    }

    // substitute t = a*x + b:  c_r = a^r * sum_{j>=r} m_j C(j,r) b^{j-r}
    double apow = 1.0;
    for (int r = 0; r < KK; ++r) {
        double s = 0.0;
        double bpow = 1.0;
        for (int j = r; j < KK; ++j) {
            s += m[j] * dC[j][r] * bpow;
            bpow *= b;
        }
        ws[p * 12 + r] = (float)(apow * s);
        apow *= a;
    }
    ws[p * 12 + 11] = 0.0f;
}

__global__ __launch_bounds__(BLK)
void decor_kernel(const float* __restrict__ in,
                  const float* __restrict__ wsp,   // wave-uniform Horner coeffs
                  float* __restrict__ out,
                  int n)
{
    const int base = blockIdx.x * (BLK * SPT) + threadIdx.x;
    const int i0 = base;
    const int i1 = base + BLK;
    const bool v0 = (i0 < n);
    const bool v1 = (i1 < n);

    const float4* in4 = (const float4*)in;
    float x0[DV], x1[DV];
    {
        float4 r0 = {0,0,0,0}, r1 = r0, r2 = r0;
        if (v0) {
            r0 = in4[(size_t)i0 * 3 + 0];
            r1 = in4[(size_t)i0 * 3 + 1];
            r2 = in4[(size_t)i0 * 3 + 2];
        }
        x0[0] = r0.x; x0[1] = r0.y; x0[2]  = r0.z; x0[3]  = r0.w;
        x0[4] = r1.x; x0[5] = r1.y; x0[6]  = r1.z; x0[7]  = r1.w;
        x0[8] = r2.x; x0[9] = r2.y; x0[10] = r2.z; x0[11] = r2.w;
    }
    {
        float4 r0 = {0,0,0,0}, r1 = r0, r2 = r0;
        if (v1) {
            r0 = in4[(size_t)i1 * 3 + 0];
            r1 = in4[(size_t)i1 * 3 + 1];
            r2 = in4[(size_t)i1 * 3 + 2];
        }
        x1[0] = r0.x; x1[1] = r0.y; x1[2]  = r0.z; x1[3]  = r0.w;
        x1[4] = r1.x; x1[5] = r1.y; x1[6]  = r1.z; x1[7]  = r1.w;
        x1[8] = r2.x; x1[9] = r2.y; x1[10] = r2.z; x1[11] = r2.w;
    }

    float a0[DV], a1[DV];
#pragma unroll
    for (int v = 0; v < DV; ++v) { a0[v] = x0[v]; a1[v] = x1[v]; }

#pragma unroll
    for (int c = 0; c < DV - 1; ++c) {
        const float xc0 = x0[c];
        const float xc1 = x1[c];
#pragma unroll
        for (int v = c + 1; v < DV; ++v) {
            // uniform, compile-time-indexed -> SMEM s_load, SGPR operands
            const float* w = wsp + (v * (v - 1) / 2 + c) * 12;
            float h0 = w[10];
            float h1 = h0;
            h0 = __builtin_fmaf(h0, xc0, w[9]); h1 = __builtin_fmaf(h1, xc1, w[9]);
            h0 = __builtin_fmaf(h0, xc0, w[8]); h1 = __builtin_fmaf(h1, xc1, w[8]);
            h0 = __builtin_fmaf(h0, xc0, w[7]); h1 = __builtin_fmaf(h1, xc1, w[7]);
            h0 = __builtin_fmaf(h0, xc0, w[6]); h1 = __builtin_fmaf(h1, xc1, w[6]);
            h0 = __builtin_fmaf(h0, xc0, w[5]); h1 = __builtin_fmaf(h1, xc1, w[5]);
            h0 = __builtin_fmaf(h0, xc0, w[4]); h1 = __builtin_fmaf(h1, xc1, w[4]);
            h0 = __builtin_fmaf(h0, xc0, w[3]); h1 = __builtin_fmaf(h1, xc1, w[3]);
            h0 = __builtin_fmaf(h0, xc0, w[2]); h1 = __builtin_fmaf(h1, xc1, w[2]);
            h0 = __builtin_fmaf(h0, xc0, w[1]); h1 = __builtin_fmaf(h1, xc1, w[1]);
            h0 = __builtin_fmaf(h0, xc0, w[0]); h1 = __builtin_fmaf(h1, xc1, w[0]);
            a0[v] = __builtin_fmaf(h0, xc0, a0[v]);
            a1[v] = __builtin_fmaf(h1, xc1, a1[v]);
        }
    }

    float4* out4 = (float4*)out;
    if (v0) {
        float4 o0 = {a0[0], a0[1], a0[2],  a0[3]};
        float4 o1 = {a0[4], a0[5], a0[6],  a0[7]};
        float4 o2 = {a0[8], a0[9], a0[10], a0[11]};
        out4[(size_t)i0 * 3 + 0] = o0;
        out4[(size_t)i0 * 3 + 1] = o1;
        out4[(size_t)i0 * 3 + 2] = o2;
    }
    if (v1) {
        float4 o0 = {a1[0], a1[1], a1[2],  a1[3]};
        float4 o1 = {a1[4], a1[5], a1[6],  a1[7]};
        float4 o2 = {a1[8], a1[9], a1[10], a1[11]};
        out4[(size_t)i1 * 3 + 0] = o0;
        out4[(size_t)i1 * 3 + 1] = o1;
        out4[(size_t)i1 * 3 + 2] = o2;
    }
}

extern "C" void kernel_launch(void* const* d_in, const int* in_sizes, int n_in,
                              void* d_out, int out_size, void* d_ws, size_t ws_size,
                              hipStream_t stream)
{
    const float* in     = (const float*)d_in[0];   // [N, 12] fp32
    const float* params = (const float*)d_in[1];   // [11, 66] fp32
    const float* pr     = (const float*)d_in[2];   // [2, 12] fp32
    float* out          = (float*)d_out;           // [N, 12] fp32
    float* ws           = (float*)d_ws;

    const int n = in_sizes[0] / DV;                // number of samples

    prep_kernel<<<1, 128, 0, stream>>>(params, pr, ws);
    const int grid = (n + BLK * SPT - 1) / (BLK * SPT);
    decor_kernel<<<grid, BLK, 0, stream>>>(in, ws, out, n);
}

// Round 6
// 119.613 us; speedup vs baseline: 1.2105x; 1.2105x over previous
//
#include <hip/hip_runtime.h>

#define DV    12
#define NP    66
#define KK    11
#define NFEAT 121        // 11 columns x 11 basis functions
#define KPAD  128        // pad to 4 K-steps of 32

// ws layout: bytes [0..4095] = W2[16][128] bf16 (binom folded, zero-padded)
//            float index 1024.. = sa[12], 1036.. = sb[12]  (t = fma(x, sa, sb))
#define WS_SA 1024
#define WS_SB 1036

typedef __attribute__((ext_vector_type(8))) short bf16x8;
typedef __attribute__((ext_vector_type(4))) float f32x4;

__device__ __constant__ float c_binom[KK] =
    {1.f, 10.f, 45.f, 120.f, 210.f, 252.f, 210.f, 120.f, 45.f, 10.f, 1.f};

__device__ __forceinline__ unsigned bfb(float f) {   // f32 -> bf16 bits, RNE
    union { float f; unsigned u; } c; c.f = f;
    return (c.u + 0x7FFFu + ((c.u >> 16) & 1u)) >> 16;
}

__global__ __launch_bounds__(256)
void prep_kernel(const float* __restrict__ params,
                 const float* __restrict__ pr,
                 void* __restrict__ wsv)
{
    unsigned short* w2 = (unsigned short*)wsv;
    float* wsf = (float*)wsv;
    const int tid = threadIdx.x;
    for (int i = tid; i < 16 * KPAD; i += 256) {
        const int v  = i >> 7;       // 0..15 (rows 12..15 pad)
        const int kk = i & 127;
        float val = 0.0f;
        if (v < DV && kk < NFEAT) {
            const int c = kk / KK;
            const int k = kk - c * KK;
            if (c < v) {
                const int p = v * (v - 1) / 2 + c;
                val = params[k * NP + p] * c_binom[k];
            }
        }
        w2[i] = (unsigned short)bfb(val);
    }
    if (tid < DV) {
        float low  = pr[tid];
        float high = pr[DV + tid];
        float w    = high - low;
        float lo   = low - 0.1f * w;
        float hi   = high + 0.1f * w;
        float inv  = 1.0f / (hi - lo);
        wsf[WS_SA + tid] = inv;
        wsf[WS_SB + tid] = -lo * inv;
    }
}

__global__ __launch_bounds__(64)
void decor_mfma(const float* __restrict__ in,
                const void* __restrict__ wsv,
                float* __restrict__ out,
                int n)
{
    __shared__ __align__(16) char lds[64 * 256];   // F[64 samples][128 bf16], XOR-swizzled

    const int l = threadIdx.x;          // 0..63
    const int q = l >> 4;               // quadrant
    const int p = l & 15;               // position in 16
    const long s0 = (long)blockIdx.x * 64;
    const unsigned swz = (unsigned)((l & 7) << 4);

    const float* wsf = (const float*)wsv;
    const char*  w2b = (const char*)wsv;

    // ---- A fragments: W2 row p, k-slots s*32 + q*8 .. +8 (8 bf16 = 16B), L1/L2 hot
    bf16x8 af[4];
#pragma unroll
    for (int s = 0; s < 4; ++s) {
        union { int4 i; bf16x8 h; } u;
        u.i = *(const int4*)(w2b + p * 256 + s * 64 + q * 16);
        af[s] = u.h;
    }

    // ---- C-init: acc[g] row q*4+r = in[sample(g,p)][q*4+r]  (identity term, exact f32)
    f32x4 acc[4];
#pragma unroll
    for (int g = 0; g < 4; ++g) {
        const long sg = s0 + 16 * g + p;
        float4 cin = make_float4(0.f, 0.f, 0.f, 0.f);
        if (q < 3 && sg < n) cin = *(const float4*)(in + sg * 12 + q * 4);
        acc[g][0] = cin.x; acc[g][1] = cin.y; acc[g][2] = cin.z; acc[g][3] = cin.w;
    }

    // ---- own sample's 12 inputs
    const long mys = s0 + l;
    float x[DV];
    {
        float4 r0 = make_float4(0.f,0.f,0.f,0.f), r1 = r0, r2 = r0;
        if (mys < n) {
            const float4* in4 = (const float4*)(in + mys * 12);
            r0 = in4[0]; r1 = in4[1]; r2 = in4[2];
        }
        x[0]=r0.x; x[1]=r0.y; x[2] =r0.z; x[3] =r0.w;
        x[4]=r1.x; x[5]=r1.y; x[6] =r1.z; x[7] =r1.w;
        x[8]=r2.x; x[9]=r2.y; x[10]=r2.z; x[11]=r2.w;
    }

    // ---- Bernstein features -> bf16 -> LDS (write b128 group as soon as complete)
    unsigned uw[64];
#pragma unroll
    for (int c = 0; c < KK; ++c) {
        const float t  = __builtin_fmaf(x[c], wsf[WS_SA + c], wsf[WS_SB + c]);
        const float u1 = 1.0f - t;
        float tp[KK];
        tp[0] = 1.0f;
#pragma unroll
        for (int k = 1; k < KK; ++k) tp[k] = tp[k - 1] * t;
        float gl[KK];
        gl[KK - 1] = x[c];                 // fold x_c into u-ladder
#pragma unroll
        for (int k = KK - 2; k >= 0; --k) gl[k] = gl[k + 1] * u1;
        float fl[KK];
        fl[0] = gl[0];
#pragma unroll
        for (int k = 1; k < KK; ++k) fl[k] = tp[k] * gl[k];

#pragma unroll
        for (int k = 0; k < KK; ++k) {
            const int idx = c * KK + k;          // compile-time
            const unsigned b = bfb(fl[k]);
            if ((idx & 1) == 0) uw[idx >> 1] = b;
            else                uw[idx >> 1] |= (b << 16);
            if ((idx & 7) == 7) {                // b128 group complete
                const int grp = idx >> 3;        // 0..14
                int4 w4 = make_int4(uw[grp*4], uw[grp*4+1], uw[grp*4+2], uw[grp*4+3]);
                *(int4*)(lds + (unsigned)l * 256u + (((unsigned)grp * 16u) ^ swz)) = w4;
            }
        }
    }
    // pad features 121..127 = 0, emit last group (words 60..63)
    uw[60] &= 0xFFFFu;
    uw[61] = 0u; uw[62] = 0u; uw[63] = 0u;
    *(int4*)(lds + (unsigned)l * 256u + ((15u * 16u) ^ swz)) =
        make_int4(uw[60], uw[61], uw[62], uw[63]);

    __syncthreads();   // single-wave block: compiles to a cheap waitcnt/barrier

    // ---- GEMM: 4 sample-groups x 4 K-steps
#pragma unroll
    for (int g = 0; g < 4; ++g) {
        const unsigned row = (unsigned)(16 * g + p);
#pragma unroll
        for (int s = 0; s < 4; ++s) {
            union { int4 i; bf16x8 h; } u;
            u.i = *(const int4*)(lds + row * 256u +
                                 (((unsigned)(s * 64 + q * 16)) ^ swz));
            acc[g] = __builtin_amdgcn_mfma_f32_16x16x32_bf16(af[s], u.h, acc[g], 0, 0, 0);
        }
    }

    // ---- store: lane (q<3) writes rows q*4..q*4+3 of sample (g,p)
#pragma unroll
    for (int g = 0; g < 4; ++g) {
        const long sg = s0 + 16 * g + p;
        if (q < 3 && sg < n) {
            float4 o = make_float4(acc[g][0], acc[g][1], acc[g][2], acc[g][3]);
            *(float4*)(out + sg * 12 + q * 4) = o;
        }
    }
}

extern "C" void kernel_launch(void* const* d_in, const int* in_sizes, int n_in,
                              void* d_out, int out_size, void* d_ws, size_t ws_size,
                              hipStream_t stream)
{
    const float* in     = (const float*)d_in[0];   // [N, 12] fp32
    const float* params = (const float*)d_in[1];   // [11, 66] fp32
    const float* pr     = (const float*)d_in[2];   // [2, 12] fp32
    float* out          = (float*)d_out;           // [N, 12] fp32

    const int n = in_sizes[0] / DV;

    prep_kernel<<<1, 256, 0, stream>>>(params, pr, d_ws);
    const int grid = (n + 63) / 64;
    decor_mfma<<<grid, 64, 0, stream>>>(in, d_ws, (float*)d_out, n);
}

// Round 11
// 113.786 us; speedup vs baseline: 1.2725x; 1.0512x over previous
//
#include <hip/hip_runtime.h>

#define DV    12
#define NP    66
#define KK    11

// ws layout: bytes [0..4095] = W2[16][128] bf16 (binom folded, zero-padded)
//            float index 1024.. = sa[12], 1036.. = sb[12]  (t = fma(x, sa, sb))
#define WS_SA 1024
#define WS_SB 1036

typedef __attribute__((ext_vector_type(8))) short bf16x8;
typedef __attribute__((ext_vector_type(4))) float f32x4;

__device__ __constant__ float c_binom[KK] =
    {1.f, 10.f, 45.f, 120.f, 210.f, 252.f, 210.f, 120.f, 45.f, 10.f, 1.f};

__device__ __forceinline__ unsigned bfb(float f) {   // f32 -> bf16 bits, RNE
    union { float f; unsigned u; } c; c.f = f;
    return (c.u + 0x7FFFu + ((c.u >> 16) & 1u)) >> 16;
}

__global__ __launch_bounds__(256)
void prep_kernel(const float* __restrict__ params,
                 const float* __restrict__ pr,
                 void* __restrict__ wsv)
{
    unsigned short* w2 = (unsigned short*)wsv;
    float* wsf = (float*)wsv;
    const int tid = threadIdx.x;
    for (int i = tid; i < 16 * 128; i += 256) {
        const int v  = i >> 7;       // 0..15 (rows 12..15 pad)
        const int kk = i & 127;
        float val = 0.0f;
        if (v < DV && kk < 121) {
            const int c = kk / KK;
            const int k = kk - c * KK;
            if (c < v) {
                const int p = v * (v - 1) / 2 + c;
                val = params[k * NP + p] * c_binom[k];
            }
        }
        w2[i] = (unsigned short)bfb(val);
    }
    if (tid < DV) {
        float low  = pr[tid];
        float high = pr[DV + tid];
        float w    = high - low;
        float lo   = low - 0.1f * w;
        float hi   = high + 0.1f * w;
        float inv  = 1.0f / (hi - lo);
        wsf[WS_SA + tid] = inv;
        wsf[WS_SB + tid] = -lo * inv;
    }
}

__global__ __launch_bounds__(256, 4)
void decor_mfma(const float* __restrict__ in,
                const void* __restrict__ wsv,
                float* __restrict__ out,
                int n)
{
    // 4 waves/block; each wave owns an 8 KB slice: [64 samples][64 feats] bf16,
    // reused for both K-halves. Real __syncthreads at reuse boundaries
    // (waves are homogeneous -> negligible lockstep cost; bulletproof ordering).
    __shared__ __align__(16) char lds_all[4][64 * 128];

    const int tid = threadIdx.x;
    const int wv  = tid >> 6;
    const int l   = tid & 63;
    char* lds = lds_all[wv];

    const int q = l >> 4;               // quadrant
    const int p = l & 15;               // position in 16
    const long s0 = (long)blockIdx.x * 256 + (long)wv * 64;
    const unsigned swz = (unsigned)((l & 7) << 4);

    const float* wsf = (const float*)wsv;
    const char*  w2b = (const char*)wsv;

    // ---- A fragments: W2 row p, k-slots s*32 + q*8 (8 bf16 = 16B), L2-hot
    bf16x8 af[4];
#pragma unroll
    for (int s = 0; s < 4; ++s) {
        union { int4 i; bf16x8 h; } u;
        u.i = *(const int4*)(w2b + p * 256 + s * 64 + q * 16);
        af[s] = u.h;
    }

    // ---- C-init: acc[g] rows q*4..q*4+3 of sample (g,p) = identity term (exact f32)
    f32x4 acc[4];
#pragma unroll
    for (int g = 0; g < 4; ++g) {
        const long sg = s0 + 16 * g + p;
        float4 cin = make_float4(0.f, 0.f, 0.f, 0.f);
        if (q < 3 && sg < n) cin = *(const float4*)(in + sg * 12 + q * 4);
        acc[g][0] = cin.x; acc[g][1] = cin.y; acc[g][2] = cin.z; acc[g][3] = cin.w;
    }

    // ---- own sample's 12 inputs
    const long mys = s0 + l;
    float x[DV];
    {
        float4 r0 = make_float4(0.f,0.f,0.f,0.f), r1 = r0, r2 = r0;
        if (mys < n) {
            const float4* in4 = (const float4*)(in + mys * 12);
            r0 = in4[0]; r1 = in4[1]; r2 = in4[2];
        }
        x[0]=r0.x; x[1]=r0.y; x[2] =r0.z; x[3] =r0.w;
        x[4]=r1.x; x[5]=r1.y; x[6] =r1.z; x[7] =r1.w;
        x[8]=r2.x; x[9]=r2.y; x[10]=r2.z; x[11]=r2.w;
    }

    unsigned uw[64];
    float pend = 0.0f;

    // ===== pass A: columns 0..5 -> features 0..65 (groups 0..7 + uw[32] carry)
#pragma unroll
    for (int c = 0; c < 6; ++c) {
        const float xc = x[c];
        const float t  = __builtin_fmaf(xc, wsf[WS_SA + c], wsf[WS_SB + c]);
        const float u1 = 1.0f - t;
        float tp[KK];
        tp[0] = 1.0f;
#pragma unroll
        for (int k = 1; k < KK; ++k) tp[k] = tp[k - 1] * t;
        float gl[KK];
        gl[KK - 1] = xc;                   // fold x_c into u-ladder
#pragma unroll
        for (int k = KK - 2; k >= 0; --k) gl[k] = gl[k + 1] * u1;
        float fl[KK];
        fl[0] = gl[0];
#pragma unroll
        for (int k = 1; k < KK; ++k) fl[k] = tp[k] * gl[k];

#pragma unroll
        for (int k = 0; k < KK; ++k) {
            const int gidx = c * KK + k;          // compile-time
            if ((gidx & 1) == 0) pend = fl[k];
            else {
                uw[gidx >> 1] = bfb(pend) | (bfb(fl[k]) << 16);
                if ((gidx & 7) == 7) {
                    const int grp = gidx >> 3;    // 0..7
                    *(int4*)(lds + (unsigned)l * 128u +
                             ((((unsigned)(grp & 7)) * 16u) ^ swz)) =
                        make_int4(uw[grp*4], uw[grp*4+1], uw[grp*4+2], uw[grp*4+3]);
                }
            }
        }
    }

    __syncthreads();   // writes A visible before reads A

    // ---- MFMA K-steps 0,1 from half A (features 0..63)
#pragma unroll
    for (int g = 0; g < 4; ++g) {
        const unsigned row = (unsigned)(16 * g + p);
#pragma unroll
        for (int s = 0; s < 2; ++s) {
            union { int4 i; bf16x8 h; } u;
            u.i = *(const int4*)(lds + row * 128u +
                                 (((unsigned)(s * 64 + q * 16)) ^ swz));
            acc[g] = __builtin_amdgcn_mfma_f32_16x16x32_bf16(af[s], u.h, acc[g], 0, 0, 0);
        }
    }

    __syncthreads();   // reads A done before writes B

    // ===== pass B: columns 6..10 -> features 66..120 (+pad) (groups 8..15 -> slots 0..7)
#pragma unroll
    for (int c = 6; c < KK; ++c) {
        const float xc = x[c];
        const float t  = __builtin_fmaf(xc, wsf[WS_SA + c], wsf[WS_SB + c]);
        const float u1 = 1.0f - t;
        float tp[KK];
        tp[0] = 1.0f;
#pragma unroll
        for (int k = 1; k < KK; ++k) tp[k] = tp[k - 1] * t;
        float gl[KK];
        gl[KK - 1] = xc;
#pragma unroll
        for (int k = KK - 2; k >= 0; --k) gl[k] = gl[k + 1] * u1;
        float fl[KK];
        fl[0] = gl[0];
#pragma unroll
        for (int k = 1; k < KK; ++k) fl[k] = tp[k] * gl[k];

#pragma unroll
        for (int k = 0; k < KK; ++k) {
            const int gidx = c * KK + k;
            if ((gidx & 1) == 0) pend = fl[k];
            else {
                uw[gidx >> 1] = bfb(pend) | (bfb(fl[k]) << 16);
                if ((gidx & 7) == 7) {
                    const int grp = gidx >> 3;    // 8..14 -> slots 0..6
                    *(int4*)(lds + (unsigned)l * 128u +
                             ((((unsigned)(grp & 7)) * 16u) ^ swz)) =
                        make_int4(uw[grp*4], uw[grp*4+1], uw[grp*4+2], uw[grp*4+3]);
                }
            }
        }
    }
    // tail: feature 120 in pend; pad 121..127 = 0; group 15 -> slot 7
    uw[60] = bfb(pend);
    *(int4*)(lds + (unsigned)l * 128u + ((7u * 16u) ^ swz)) =
        make_int4(uw[60], 0, 0, 0);

    __syncthreads();   // writes B visible before reads B

    // ---- MFMA K-steps 2,3 from half B (features 64..127)
#pragma unroll
    for (int g = 0; g < 4; ++g) {
        const unsigned row = (unsigned)(16 * g + p);
#pragma unroll
        for (int s = 2; s < 4; ++s) {
            union { int4 i; bf16x8 h; } u;
            u.i = *(const int4*)(lds + row * 128u +
                                 (((unsigned)((s - 2) * 64 + q * 16)) ^ swz));
            acc[g] = __builtin_amdgcn_mfma_f32_16x16x32_bf16(af[s], u.h, acc[g], 0, 0, 0);
        }
    }

    // ---- store: lane (q<3) writes rows q*4..q*4+3 of sample (g,p)
#pragma unroll
    for (int g = 0; g < 4; ++g) {
        const long sg = s0 + 16 * g + p;
        if (q < 3 && sg < n) {
            float4 o = make_float4(acc[g][0], acc[g][1], acc[g][2], acc[g][3]);
            *(float4*)(out + sg * 12 + q * 4) = o;
        }
    }
}

extern "C" void kernel_launch(void* const* d_in, const int* in_sizes, int n_in,
                              void* d_out, int out_size, void* d_ws, size_t ws_size,
                              hipStream_t stream)
{
    const float* in     = (const float*)d_in[0];   // [N, 12] fp32
    const float* params = (const float*)d_in[1];   // [11, 66] fp32
    const float* pr     = (const float*)d_in[2];   // [2, 12] fp32
    float* out          = (float*)d_out;           // [N, 12] fp32

    const int n = in_sizes[0] / DV;

    prep_kernel<<<1, 256, 0, stream>>>(params, pr, d_ws);
    const int grid = (n + 255) / 256;
    decor_mfma<<<grid, 256, 0, stream>>>(in, d_ws, out, n);
}